// Round 6
// baseline (20.295 us; speedup 1.0000x reference)
//
#include <hip/hip_runtime.h>
#include <math.h>

// Quanvolution via Pauli back-propagation (derivation R1, validated R1-R4):
//  alpha_q = theta_q + w0_q; A..D = cos(alpha_q), a..d = sin(alpha_q):
//   z0 = K0*A  + K1*ab
//   z1 = K2*B  + K3*A*bc + K4*ac
//   z2 = K5*AC + K6*B*cd + K7*A*bd + K8*ab*C + K9*ad
//   z3 = L1*BD + L2*AC*d + L3*Bc + L4*Ab*cD + L5*Ab + L6*ab*Cd + L7*ac*D + L8*a
//
// R5: one wave = FOUR images. Per k-chunk iter the 10 W float4s are loaded
// ONCE into VGPRs and reused by all 4 images (acc[4][10]) -> W cache traffic
// per CU drops 4x vs R4 (the R4 binder: 32 waves/CU x 31.4 KB ~ 1.1 MB/CU).
// Still no LDS, no barriers.
#define INV2PI 0.15915494309189535f

__device__ __forceinline__ float rfl(float v) {
    return __int_as_float(__builtin_amdgcn_readfirstlane(__float_as_int(v)));
}

__global__ __launch_bounds__(256) void quanv_w4_kernel(
    const float* __restrict__ x,     // [B, 784]
    const float* __restrict__ wts,   // [2, 4]
    const float* __restrict__ W,     // [10, 784]
    const float* __restrict__ bias,  // [10]
    float* __restrict__ out,         // [B, 10]
    int B)
{
    const int lane  = threadIdx.x & 63;
    const int img0  = (blockIdx.x * 4 + (threadIdx.x >> 6)) * 4;  // 4 imgs/wave
    if (img0 >= B) return;                                        // wave-uniform

    // ---- uniform weight prep; constants pinned to SGPRs ----
    float w0r[4], cw1[4], sw1[4];
#pragma unroll
    for (int q = 0; q < 4; ++q) {
        w0r[q] = rfl(wts[q] * INV2PI);
        float r = wts[4 + q] * INV2PI;
        r -= floorf(r);
        cw1[q] = __builtin_amdgcn_cosf(r);
        sw1[q] = __builtin_amdgcn_sinf(r);
    }
    const float cc  = cw1[0]*cw1[1], cs = cw1[0]*sw1[1];
    const float sc  = sw1[0]*cw1[1], ss = sw1[0]*sw1[1];
    const float ccc = cc*cw1[2], ccs = cc*sw1[2], csc = cs*cw1[2], css = cs*sw1[2];
    const float scc = sc*cw1[2], ssc = ss*cw1[2], sss = ss*sw1[2];
    const float K0 = rfl(cw1[0]),       K1 = rfl(-sw1[0]);
    const float K2 = rfl(cc),           K3 = rfl(-cs),          K4 = rfl(ss);
    const float K5 = rfl(ccc),          K6 = rfl(-ccs),         K7 = rfl(css);
    const float K8 = rfl(-scc),         K9 = rfl(-sss);
    const float L1 = rfl(ccc*cw1[3]),   L2 = rfl(-ccc*sw1[3]);
    const float L3 = rfl(ccs*sw1[3]),   L4 = rfl(-csc*cw1[3]);
    const float L5 = rfl(-css*sw1[3]),  L6 = rfl(scc*sw1[3]);
    const float L7 = rfl(ssc*cw1[3]),   L8 = rfl(sss*sw1[3]);

    float acc[4][10];
#pragma unroll
    for (int im = 0; im < 4; ++im)
#pragma unroll
        for (int cl = 0; cl < 10; ++cl) acc[im][cl] = 0.f;

    // ---- 196 k-chunks tiled by 64 lanes x 4 iters; W loaded once per chunk ----
#pragma unroll
    for (int i = 0; i < 4; ++i) {
        const int p = i * 64 + lane;
        if (p < 196) {
            const int pi = p / 14, pj = p - pi * 14;
            const int xoff = pi * 56 + pj * 2;

            float4 wv[10];
#pragma unroll
            for (int cl = 0; cl < 10; ++cl)
                wv[cl] = *(const float4*)(W + cl * 784 + p * 4);

#pragma unroll
            for (int im = 0; im < 4; ++im) {
                if (img0 + im < B) {
                    const float* xp = x + (size_t)(img0 + im) * 784 + xoff;
                    const float2 t0 = *(const float2*)xp;
                    const float2 t1 = *(const float2*)(xp + 28);

                    float r;
                    r = fmaf(t0.x, INV2PI, w0r[0]); r -= floorf(r);
                    const float a  = __builtin_amdgcn_sinf(r), A  = __builtin_amdgcn_cosf(r);
                    r = fmaf(t0.y, INV2PI, w0r[1]); r -= floorf(r);
                    const float b  = __builtin_amdgcn_sinf(r), Bv = __builtin_amdgcn_cosf(r);
                    r = fmaf(t1.x, INV2PI, w0r[2]); r -= floorf(r);
                    const float c  = __builtin_amdgcn_sinf(r), C  = __builtin_amdgcn_cosf(r);
                    r = fmaf(t1.y, INV2PI, w0r[3]); r -= floorf(r);
                    const float d  = __builtin_amdgcn_sinf(r), D  = __builtin_amdgcn_cosf(r);

                    const float ab=a*b, bc=b*c, ac=a*c, cd=c*d, bd=b*d, ad=a*d;
                    const float AC=A*C, Ab=A*b, Bc=Bv*c, BD=Bv*D, cD=c*D, Cd=C*d;

                    const float z0 = fmaf(K0, A,  K1*ab);
                    const float z1 = fmaf(K2, Bv, fmaf(K3, A*bc, K4*ac));
                    const float z2 = fmaf(K5, AC, fmaf(K6, Bv*cd,
                                     fmaf(K7, A*bd, fmaf(K8, ab*C, K9*ad))));
                    const float z3 = fmaf(L1, BD, fmaf(L2, AC*d, fmaf(L3, Bc,
                                     fmaf(L4, Ab*cD, fmaf(L5, Ab, fmaf(L6, ab*Cd,
                                     fmaf(L7, ac*D, L8*a)))))));

#pragma unroll
                    for (int cl = 0; cl < 10; ++cl)
                        acc[im][cl] = fmaf(z0, wv[cl].x, fmaf(z1, wv[cl].y,
                                      fmaf(z2, wv[cl].z, fmaf(z3, wv[cl].w, acc[im][cl]))));
                }
            }
        }
    }

    // ---- per image: butterfly reduce, log_softmax, store ----
#pragma unroll
    for (int im = 0; im < 4; ++im) {
        if (img0 + im < B) {
            float lg[10];
#pragma unroll
            for (int cl = 0; cl < 10; ++cl) {
                float v = acc[im][cl];
                v += __shfl_xor(v, 1, 64);
                v += __shfl_xor(v, 2, 64);
                v += __shfl_xor(v, 4, 64);
                v += __shfl_xor(v, 8, 64);
                v += __shfl_xor(v, 16, 64);
                v += __shfl_xor(v, 32, 64);
                lg[cl] = v + bias[cl];
            }
            float m = lg[0];
#pragma unroll
            for (int cl = 1; cl < 10; ++cl) m = fmaxf(m, lg[cl]);
            float s = 0.f;
#pragma unroll
            for (int cl = 0; cl < 10; ++cl) s += __expf(lg[cl] - m);
            const float lse = m + __logf(s);

            if (lane == 0) {
                float* op = out + (size_t)(img0 + im) * 10;
                *(float2*)(op + 0) = make_float2(lg[0] - lse, lg[1] - lse);
                *(float2*)(op + 2) = make_float2(lg[2] - lse, lg[3] - lse);
                *(float2*)(op + 4) = make_float2(lg[4] - lse, lg[5] - lse);
                *(float2*)(op + 6) = make_float2(lg[6] - lse, lg[7] - lse);
                *(float2*)(op + 8) = make_float2(lg[8] - lse, lg[9] - lse);
            }
        }
    }
}

extern "C" void kernel_launch(void* const* d_in, const int* in_sizes, int n_in,
                              void* d_out, int out_size, void* d_ws, size_t ws_size,
                              hipStream_t stream) {
    const float* x    = (const float*)d_in[0];
    const float* wts  = (const float*)d_in[1];
    const float* W    = (const float*)d_in[2];
    const float* bias = (const float*)d_in[3];
    float* out        = (float*)d_out;

    const int B = in_sizes[0] / 784;
    const int blocks = (B + 15) / 16;   // 4 waves/block, 4 images/wave
    quanv_w4_kernel<<<blocks, 256, 0, stream>>>(x, wts, W, bias, out, B);
}

// Round 7
// 18.730 us; speedup vs baseline: 1.0835x; 1.0835x over previous
//
#include <hip/hip_runtime.h>
#include <math.h>

// Quanvolution via Pauli back-propagation (derivation R1, validated R1-R5):
//  alpha_q = theta_q + w0_q; A..D = cos(alpha_q), a..d = sin(alpha_q):
//   z0 = K0*A  + K1*ab
//   z1 = K2*B  + K3*A*bc + K4*ac
//   z2 = K5*AC + K6*B*cd + K7*A*bd + K8*ab*C + K9*ad
//   z3 = L1*BD + L2*AC*d + L3*Bc + L4*Ab*cD + L5*Ab + L6*ab*Cd + L7*ac*D + L8*a
//
// R6: 4 images/wave (W float4s loaded once per k-chunk, reused x4 -> 4x less
// L1 W-traffic, the R4 binder) AND K-split: partner waves each do 98 of the
// 196 patches -> 4096 waves total = 4/SIMD occupancy (the R5 failure).
// Partial logits merged via a tiny LDS tree.
#define INV2PI 0.15915494309189535f

__device__ __forceinline__ float rfl(float v) {
    return __int_as_float(__builtin_amdgcn_readfirstlane(__float_as_int(v)));
}

__global__ __launch_bounds__(256, 4) void quanv_ks_kernel(
    const float* __restrict__ x,     // [B, 784]
    const float* __restrict__ wts,   // [2, 4]
    const float* __restrict__ W,     // [10, 784]
    const float* __restrict__ bias,  // [10]
    float* __restrict__ out,         // [B, 10]
    int B)
{
    __shared__ float part[4][8][40];   // [wave][lane-octet][im*10+cl]
    __shared__ float logits[8][10];
    __shared__ float lsev[8];

    const int tid   = threadIdx.x;
    const int wave  = tid >> 6, lane = tid & 63;
    const int group = wave >> 1;        // 0,1: which 4-image set
    const int half  = wave & 1;         // 0,1: which 98-patch half
    const int imgb  = blockIdx.x * 8 + group * 4;

    // ---- uniform weight prep; constants pinned to SGPRs ----
    float w0r[4], cw1[4], sw1[4];
#pragma unroll
    for (int q = 0; q < 4; ++q) {
        w0r[q] = rfl(wts[q] * INV2PI);
        float r = wts[4 + q] * INV2PI;
        r -= floorf(r);
        cw1[q] = __builtin_amdgcn_cosf(r);
        sw1[q] = __builtin_amdgcn_sinf(r);
    }
    const float cc  = cw1[0]*cw1[1], cs = cw1[0]*sw1[1];
    const float sc  = sw1[0]*cw1[1], ss = sw1[0]*sw1[1];
    const float ccc = cc*cw1[2], ccs = cc*sw1[2], csc = cs*cw1[2], css = cs*sw1[2];
    const float scc = sc*cw1[2], ssc = ss*cw1[2], sss = ss*sw1[2];
    const float K0 = rfl(cw1[0]),       K1 = rfl(-sw1[0]);
    const float K2 = rfl(cc),           K3 = rfl(-cs),          K4 = rfl(ss);
    const float K5 = rfl(ccc),          K6 = rfl(-ccs),         K7 = rfl(css);
    const float K8 = rfl(-scc),         K9 = rfl(-sss);
    const float L1 = rfl(ccc*cw1[3]),   L2 = rfl(-ccc*sw1[3]);
    const float L3 = rfl(ccs*sw1[3]),   L4 = rfl(-csc*cw1[3]);
    const float L5 = rfl(-css*sw1[3]),  L6 = rfl(scc*sw1[3]);
    const float L7 = rfl(ssc*cw1[3]),   L8 = rfl(sss*sw1[3]);

    float acc[4][10];
#pragma unroll
    for (int im = 0; im < 4; ++im)
#pragma unroll
        for (int cl = 0; cl < 10; ++cl) acc[im][cl] = 0.f;

    // ---- this wave's 98 patches: 64 + 34(masked) ----
#pragma unroll
    for (int it = 0; it < 2; ++it) {
        if (it == 0 || lane < 34) {
            const int p  = half * 98 + it * 64 + lane;
            const int pi = p / 14, pj = p - pi * 14;
            const int xoff = pi * 56 + pj * 2;

            float z[4][4];
#pragma unroll
            for (int im = 0; im < 4; ++im) {
                const int img = imgb + im;
                if (img < B) {
                    const float* xp = x + (size_t)img * 784 + xoff;
                    const float2 t0 = *(const float2*)xp;
                    const float2 t1 = *(const float2*)(xp + 28);

                    float r;
                    r = fmaf(t0.x, INV2PI, w0r[0]); r -= floorf(r);
                    const float a  = __builtin_amdgcn_sinf(r), A  = __builtin_amdgcn_cosf(r);
                    r = fmaf(t0.y, INV2PI, w0r[1]); r -= floorf(r);
                    const float b  = __builtin_amdgcn_sinf(r), Bv = __builtin_amdgcn_cosf(r);
                    r = fmaf(t1.x, INV2PI, w0r[2]); r -= floorf(r);
                    const float c  = __builtin_amdgcn_sinf(r), C  = __builtin_amdgcn_cosf(r);
                    r = fmaf(t1.y, INV2PI, w0r[3]); r -= floorf(r);
                    const float d  = __builtin_amdgcn_sinf(r), D  = __builtin_amdgcn_cosf(r);

                    const float ab=a*b, bc=b*c, ac=a*c, cd=c*d, bd=b*d, ad=a*d;
                    const float AC=A*C, Ab=A*b, Bc=Bv*c, BD=Bv*D, cD=c*D, Cd=C*d;

                    z[im][0] = fmaf(K0, A,  K1*ab);
                    z[im][1] = fmaf(K2, Bv, fmaf(K3, A*bc, K4*ac));
                    z[im][2] = fmaf(K5, AC, fmaf(K6, Bv*cd,
                               fmaf(K7, A*bd, fmaf(K8, ab*C, K9*ad))));
                    z[im][3] = fmaf(L1, BD, fmaf(L2, AC*d, fmaf(L3, Bc,
                               fmaf(L4, Ab*cD, fmaf(L5, Ab, fmaf(L6, ab*Cd,
                               fmaf(L7, ac*D, L8*a)))))));
                } else {
                    z[im][0] = z[im][1] = z[im][2] = z[im][3] = 0.f;
                }
            }

            // W float4 loaded once per class, reused by all 4 images
#pragma unroll
            for (int cl = 0; cl < 10; ++cl) {
                const float4 wv = *(const float4*)(W + cl * 784 + p * 4);
#pragma unroll
                for (int im = 0; im < 4; ++im)
                    acc[im][cl] = fmaf(z[im][0], wv.x, fmaf(z[im][1], wv.y,
                                  fmaf(z[im][2], wv.z, fmaf(z[im][3], wv.w, acc[im][cl]))));
            }
        }
    }

    // ---- 3-level butterfly (within 8-lane octets), dump octet sums to LDS ----
#pragma unroll
    for (int im = 0; im < 4; ++im)
#pragma unroll
        for (int cl = 0; cl < 10; ++cl) {
            float v = acc[im][cl];
            v += __shfl_xor(v, 1, 64);
            v += __shfl_xor(v, 2, 64);
            v += __shfl_xor(v, 4, 64);
            if ((lane & 7) == 0) part[wave][lane >> 3][im * 10 + cl] = v;
        }
    __syncthreads();

    // ---- cross-octet + cross-wave reduce: 80 threads, one (group,im,cl) each ----
    if (tid < 80) {
        const int g  = tid / 40;
        const int vv = tid - g * 40;
        const int im = vv / 10, cl = vv - im * 10;
        float s = 0.f;
#pragma unroll
        for (int l = 0; l < 8; ++l)
            s += part[2 * g][l][vv] + part[2 * g + 1][l][vv];
        logits[g * 4 + im][cl] = s + bias[cl];
    }
    __syncthreads();

    // ---- per-image log-sum-exp (8 threads) ----
    if (tid < 8) {
        if (blockIdx.x * 8 + tid < B) {
            float m = logits[tid][0];
#pragma unroll
            for (int cl = 1; cl < 10; ++cl) m = fmaxf(m, logits[tid][cl]);
            float s = 0.f;
#pragma unroll
            for (int cl = 0; cl < 10; ++cl) s += __expf(logits[tid][cl] - m);
            lsev[tid] = m + __logf(s);
        }
    }
    __syncthreads();

    // ---- store ----
    if (tid < 80) {
        const int imloc = tid / 10, cl = tid - (tid / 10) * 10;
        const int img = blockIdx.x * 8 + imloc;
        if (img < B)
            out[(size_t)img * 10 + cl] = logits[imloc][cl] - lsev[imloc];
    }
}

extern "C" void kernel_launch(void* const* d_in, const int* in_sizes, int n_in,
                              void* d_out, int out_size, void* d_ws, size_t ws_size,
                              hipStream_t stream) {
    const float* x    = (const float*)d_in[0];
    const float* wts  = (const float*)d_in[1];
    const float* W    = (const float*)d_in[2];
    const float* bias = (const float*)d_in[3];
    float* out        = (float*)d_out;

    const int B = in_sizes[0] / 784;
    const int blocks = (B + 7) / 8;   // 8 images/block: 2 groups x (2 k-split waves)
    quanv_ks_kernel<<<blocks, 256, 0, stream>>>(x, wts, W, bias, out, B);
}